// Round 11
// baseline (274.594 us; speedup 1.0000x reference)
//
#include <hip/hip_runtime.h>
#include <math.h>

#define NEG_SLOPE 0.2f
#define GEPS 1e-5f

typedef __attribute__((ext_vector_type(8))) short short8;
typedef __attribute__((ext_vector_type(4))) float floatx4;

__device__ __forceinline__ float wave_reduce_sum(float v) {
#pragma unroll
    for (int o = 32; o > 0; o >>= 1) v += __shfl_down(v, o);
    return v;
}

__device__ __forceinline__ ushort f2bf(float f) {
    union { float f; unsigned int i; } c;
    c.f = f;
    unsigned int b = c.i;
    b += 0x7fffu + ((b >> 16) & 1u);
    return (ushort)(b >> 16);
}

__device__ __forceinline__ float bf2f(ushort u) {
    union { unsigned int i; float f; } c;
    c.i = (unsigned int)u << 16;
    return c.f;
}

__device__ __forceinline__ float2 unpack_bf2(unsigned int u) {
    union { unsigned int i; float f; } a, b;
    a.i = u << 16;            // low ushort -> even col
    b.i = u & 0xffff0000u;    // high ushort -> odd col
    return make_float2(a.f, b.f);
}

__device__ __forceinline__ unsigned int pack_bf2(float lo, float hi) {
    return (unsigned int)f2bf(lo) | ((unsigned int)f2bf(hi) << 16);
}

__device__ __forceinline__ float lrelu(float v) {
    return (v > 0.f) ? v : v * NEG_SLOPE;
}

__device__ __forceinline__ float elu_fast(float v) {
    return (v > 0.f) ? v : (__expf(v) - 1.f);
}

// ---------------- merged prologue ----------------
// blocks [0, 16)   : W2 -> bf16 MFMA B-fragment layout
// block  16        : attn consts: C1 (We1.ae1), C2 (We2.ae2), P_s1/P_d1 (W1@as1 / W1@ad1, 3/head)
// blocks [17, 273) : edge_attr column sums + degree histogram
__global__ __launch_bounds__(256) void k_pre(
    const float* __restrict__ W1, const float* __restrict__ as1, const float* __restrict__ ad1,
    const float* __restrict__ ea, const int* __restrict__ dst,
    const float* __restrict__ W2, const float* __restrict__ We1,
    const float* __restrict__ ae1, const float* __restrict__ We2,
    const float* __restrict__ ae2,
    float* __restrict__ ea_sum, int* __restrict__ deg, uint4* __restrict__ Bfrag,
    float* __restrict__ C1, float* __restrict__ C2, float* __restrict__ Ps,
    float* __restrict__ Pd, int E) {
    int b = blockIdx.x;
    if (b < 16) {
        int t = b * 256 + threadIdx.x;  // 4096 threads
        int c = t >> 9, kk = (t >> 6) & 7, L = t & 63;
        int q = L >> 4, n = c * 16 + (L & 15);
        int k0 = kk * 32 + q * 8;
        unsigned int u0 = pack_bf2(W2[(k0 + 0) * 128 + n], W2[(k0 + 1) * 128 + n]);
        unsigned int u1 = pack_bf2(W2[(k0 + 2) * 128 + n], W2[(k0 + 3) * 128 + n]);
        unsigned int u2 = pack_bf2(W2[(k0 + 4) * 128 + n], W2[(k0 + 5) * 128 + n]);
        unsigned int u3 = pack_bf2(W2[(k0 + 6) * 128 + n], W2[(k0 + 7) * 128 + n]);
        Bfrag[t] = make_uint4(u0, u1, u2, u3);
        return;
    }
    if (b == 16) {
        int t = threadIdx.x, h = t >> 6, lane = t & 63;
        float p0 = We1[t] * ae1[t];
        float p1 = We1[256 + t] * ae1[t];
        p0 = wave_reduce_sum(p0);
        p1 = wave_reduce_sum(p1);
        if (lane == 0) { C1[h] = p0; C1[4 + h] = p1; }
        float av = as1[t], dv = ad1[t];
#pragma unroll
        for (int k = 0; k < 3; ++k) {
            float wv = W1[k * 256 + t];
            float ps = wave_reduce_sum(wv * av);
            float pd = wave_reduce_sum(wv * dv);
            if (lane == 0) { Ps[h * 3 + k] = ps; Pd[h * 3 + k] = pd; }
        }
        if (t < 128) {
            float q0 = We2[t] * ae2[t];
            float q1 = We2[128 + t] * ae2[t];
            q0 = wave_reduce_sum(q0);
            q1 = wave_reduce_sum(q1);
            if (lane == 0) { C2[h] = q0; C2[2 + h] = q1; }
        }
        return;
    }
    b -= 17;
    const float2* ea2 = (const float2*)ea;
    float s0 = 0.f, s1 = 0.f;
    for (int e = b * 256 + threadIdx.x; e < E; e += 256 * 256) {
        float2 v = ea2[e];
        s0 += v.x; s1 += v.y;
        atomicAdd(&deg[dst[e]], 1);
    }
    s0 = wave_reduce_sum(s0);
    s1 = wave_reduce_sum(s1);
    if ((threadIdx.x & 63) == 0) {
        atomicAdd(&ea_sum[0], s0);
        atomicAdd(&ea_sum[1], s1);
    }
}

// ---------------- single-pass CSR scan: redundant block-prefix (no bsum, one launch) ----
// also: lE1/lE2 self-loop consts, node record ndr = {x(3),_, as1(4)}, and al_d1 fill.
__global__ __launch_bounds__(1024) void k_scan(const int* __restrict__ deg,
                                               int* __restrict__ row_ptr,
                                               const float* __restrict__ ea_sum,
                                               const float* __restrict__ C1,
                                               const float* __restrict__ C2,
                                               const float* __restrict__ Ps,
                                               const float* __restrict__ Pd,
                                               const float* __restrict__ x,
                                               float4* __restrict__ ndr,
                                               float* __restrict__ al_d1,
                                               float* __restrict__ lE1,
                                               float* __restrict__ lE2, int N, int E) {
    __shared__ int tmp[1024];
    __shared__ int wsum[16];
    int tid = threadIdx.x;
    int i = blockIdx.x * 1024 + tid;
    int v = (i < N) ? deg[i] : 0;
    tmp[tid] = v;
    // redundant prefix: every block sums deg[0 .. b*1024) itself (<=48 ints/thread, L2-hot)
    int lim = blockIdx.x * 1024;
    int pre = 0;
    for (int j = tid; j < lim; j += 1024) pre += deg[j];
#pragma unroll
    for (int o = 32; o > 0; o >>= 1) pre += __shfl_down(pre, o);
    if ((tid & 63) == 0) wsum[tid >> 6] = pre;
    __syncthreads();
    int off = 0;
#pragma unroll
    for (int k = 0; k < 16; ++k) off += wsum[k];
    // inclusive scan of this block's tile
#pragma unroll
    for (int o = 1; o < 1024; o <<= 1) {
        int t_ = (tid >= o) ? tmp[tid - o] : 0;
        __syncthreads();
        tmp[tid] += t_;
        __syncthreads();
    }
    if (i == 0) row_ptr[0] = 0;
    if (blockIdx.x == 0 && tid < 4) {
        float m0 = ea_sum[0] / (float)E, m1 = ea_sum[1] / (float)E;
        lE1[tid] = m0 * C1[tid] + m1 * C1[4 + tid];
        if (tid < 2) lE2[tid] = m0 * C2[tid] + m1 * C2[2 + tid];
    }
    if (i < N) {
        row_ptr[i + 1] = tmp[tid] + off;
        float x0 = x[3 * i], x1 = x[3 * i + 1], x2 = x[3 * i + 2];
        float4 sv, dv;
        sv.x = fmaf(x0, Ps[0], fmaf(x1, Ps[1], x2 * Ps[2]));
        sv.y = fmaf(x0, Ps[3], fmaf(x1, Ps[4], x2 * Ps[5]));
        sv.z = fmaf(x0, Ps[6], fmaf(x1, Ps[7], x2 * Ps[8]));
        sv.w = fmaf(x0, Ps[9], fmaf(x1, Ps[10], x2 * Ps[11]));
        dv.x = fmaf(x0, Pd[0], fmaf(x1, Pd[1], x2 * Pd[2]));
        dv.y = fmaf(x0, Pd[3], fmaf(x1, Pd[4], x2 * Pd[5]));
        dv.z = fmaf(x0, Pd[6], fmaf(x1, Pd[7], x2 * Pd[8]));
        dv.w = fmaf(x0, Pd[9], fmaf(x1, Pd[10], x2 * Pd[11]));
        ndr[2 * (size_t)i] = make_float4(x0, x1, x2, 0.f);
        ndr[2 * (size_t)i + 1] = sv;
        *(float4*)(al_d1 + 4 * (size_t)i) = dv;
    }
}

// ---------------- CSR scatter: pure 16B record {src, ea.x, ea.y} ----------------
__global__ void k_scat(const int* __restrict__ dst, const int* __restrict__ src,
                       const float* __restrict__ ea, const int* __restrict__ row_ptr,
                       int* __restrict__ deg, float4* __restrict__ ed4, int E) {
    int e = blockIdx.x * 256 + threadIdx.x;
    if (e >= E) return;
    int d = dst[e];
    int r = atomicSub(&deg[d], 1);
    int slot = row_ptr[d] + r - 1;
    float2 v = ((const float2*)ea)[e];
    ed4[slot] = make_float4(__int_as_float(src[e]), v.x, v.y, 0.f);
}

// ---------------- layer-1 aggregation in x-space, inline weights, ONE-PASS ----------
__global__ __launch_bounds__(256) void k_agg1(const float4* __restrict__ ndr,
                                              const int* __restrict__ row_ptr,
                                              const float4* __restrict__ ed4,
                                              const float* __restrict__ al_d,
                                              const float* __restrict__ C1,
                                              const float* __restrict__ lE,
                                              float4* __restrict__ uarr, int N) {
    int l = threadIdx.x & 31;
    int grp = threadIdx.x >> 5;
    int n = blockIdx.x * 8 + grp;
    if (n >= N) return;
    int hh = l >> 3;  // head owned by this lane
    float4 adn = *(const float4*)(al_d + 4 * (size_t)n);
    float4 c1a = *(const float4*)C1;       // ea.x coef per head
    float4 c1b = *(const float4*)(C1 + 4); // ea.y coef per head
    float4 ndx = ndr[2 * (size_t)n];       // own x
    float4 nas = ndr[2 * (size_t)n + 1];   // own al_s
    float ws0 = __expf(lrelu(nas.x + adn.x + lE[0]));
    float ws1 = __expf(lrelu(nas.y + adn.y + lE[1]));
    float ws2 = __expf(lrelu(nas.z + adn.z + lE[2]));
    float ws3 = __expf(lrelu(nas.w + adn.w + lE[3]));
    float z[12];
    float ds[4];
#pragma unroll
    for (int k = 0; k < 12; ++k) z[k] = 0.f;
#pragma unroll
    for (int k = 0; k < 4; ++k) ds[k] = 0.f;
    int i0 = row_ptr[n];
    int cnt = row_ptr[n + 1] - i0;
    for (int j = l; j < cnt; j += 32) {
        float4 m = ed4[i0 + j];
        int s = __float_as_int(m.x);
        float4 xr = ndr[2 * (size_t)s];
        float4 as = ndr[2 * (size_t)s + 1];
        float w0 = __expf(lrelu(as.x + adn.x + m.y * c1a.x + m.z * c1b.x));
        float w1 = __expf(lrelu(as.y + adn.y + m.y * c1a.y + m.z * c1b.y));
        float w2 = __expf(lrelu(as.z + adn.z + m.y * c1a.z + m.z * c1b.z));
        float w3 = __expf(lrelu(as.w + adn.w + m.y * c1a.w + m.z * c1b.w));
        z[0] = fmaf(w0, xr.x, z[0]); z[1] = fmaf(w0, xr.y, z[1]); z[2] = fmaf(w0, xr.z, z[2]);
        z[3] = fmaf(w1, xr.x, z[3]); z[4] = fmaf(w1, xr.y, z[4]); z[5] = fmaf(w1, xr.z, z[5]);
        z[6] = fmaf(w2, xr.x, z[6]); z[7] = fmaf(w2, xr.y, z[7]); z[8] = fmaf(w2, xr.z, z[8]);
        z[9] = fmaf(w3, xr.x, z[9]); z[10] = fmaf(w3, xr.y, z[10]); z[11] = fmaf(w3, xr.z, z[11]);
        ds[0] += w0; ds[1] += w1; ds[2] += w2; ds[3] += w3;
    }
    // reduce-scatter stage 1 (xor 16): lo lanes keep heads {0,1}, hi lanes heads {2,3}
    bool hi16 = (l & 16) != 0;
    float a0, a1, a2, a3, a4, a5, a6, a7, gv, rv;
    gv = hi16 ? z[0] : z[6];  rv = __shfl_xor(gv, 16); a0 = (hi16 ? z[6] : z[0]) + rv;
    gv = hi16 ? z[1] : z[7];  rv = __shfl_xor(gv, 16); a1 = (hi16 ? z[7] : z[1]) + rv;
    gv = hi16 ? z[2] : z[8];  rv = __shfl_xor(gv, 16); a2 = (hi16 ? z[8] : z[2]) + rv;
    gv = hi16 ? z[3] : z[9];  rv = __shfl_xor(gv, 16); a3 = (hi16 ? z[9] : z[3]) + rv;
    gv = hi16 ? z[4] : z[10]; rv = __shfl_xor(gv, 16); a4 = (hi16 ? z[10] : z[4]) + rv;
    gv = hi16 ? z[5] : z[11]; rv = __shfl_xor(gv, 16); a5 = (hi16 ? z[11] : z[5]) + rv;
    gv = hi16 ? ds[0] : ds[2]; rv = __shfl_xor(gv, 16); a6 = (hi16 ? ds[2] : ds[0]) + rv;
    gv = hi16 ? ds[1] : ds[3]; rv = __shfl_xor(gv, 16); a7 = (hi16 ? ds[3] : ds[1]) + rv;
    // stage 2 (xor 8): keep own head
    bool hi8 = (l & 8) != 0;
    float c0v, c1v, c2v, c3v;
    gv = hi8 ? a0 : a3; rv = __shfl_xor(gv, 8); c0v = (hi8 ? a3 : a0) + rv;
    gv = hi8 ? a1 : a4; rv = __shfl_xor(gv, 8); c1v = (hi8 ? a4 : a1) + rv;
    gv = hi8 ? a2 : a5; rv = __shfl_xor(gv, 8); c2v = (hi8 ? a5 : a2) + rv;
    gv = hi8 ? a6 : a7; rv = __shfl_xor(gv, 8); c3v = (hi8 ? a7 : a6) + rv;
    // stages 3-5: full butterfly within the 8-lane head group
#pragma unroll
    for (int o = 4; o > 0; o >>= 1) {
        c0v += __shfl_xor(c0v, o);
        c1v += __shfl_xor(c1v, o);
        c2v += __shfl_xor(c2v, o);
        c3v += __shfl_xor(c3v, o);
    }
    // self-loop for the owned head
    float wsh = (hh == 0) ? ws0 : (hh == 1) ? ws1 : (hh == 2) ? ws2 : ws3;
    c0v = fmaf(wsh, ndx.x, c0v);
    c1v = fmaf(wsh, ndx.y, c1v);
    c2v = fmaf(wsh, ndx.z, c2v);
    c3v += wsh;
    if ((l & 7) == 0) {
        float inv = 1.f / c3v;
        uarr[(size_t)n * 4 + hh] = make_float4(c0v * inv, c1v * inv, c2v * inv, 0.f);
    }
}

// ---------------- per-head moments of u: Su(3) + Suu^T(6) -> 36 floats ----------------
__global__ __launch_bounds__(256) void k_mom(const float4* __restrict__ uarr,
                                             float* __restrict__ mom, int N4) {
    int t = threadIdx.x;
    float m[9] = {0.f, 0.f, 0.f, 0.f, 0.f, 0.f, 0.f, 0.f, 0.f};
    for (int i = blockIdx.x * 256 + t; i < N4; i += gridDim.x * 256) {
        float4 u = uarr[i];
        m[0] += u.x; m[1] += u.y; m[2] += u.z;
        m[3] = fmaf(u.x, u.x, m[3]);
        m[4] = fmaf(u.y, u.y, m[4]);
        m[5] = fmaf(u.z, u.z, m[5]);
        m[6] = fmaf(u.x, u.y, m[6]);
        m[7] = fmaf(u.x, u.z, m[7]);
        m[8] = fmaf(u.y, u.z, m[8]);
    }
    __shared__ float ls[256 * 9];
#pragma unroll
    for (int k = 0; k < 9; ++k) ls[t * 9 + k] = m[k];
    __syncthreads();
    if (t < 36) {
        int h = t / 9, k = t - h * 9;
        float s = 0.f;
        for (int tt = h; tt < 256; tt += 4) s += ls[tt * 9 + k];
        atomicAdd(&mom[t], s);
    }
}

// ---------------- MFMA GEMM2: expand out1 from uarr + analytic GraphNorm coefs ----------
__global__ __launch_bounds__(256) void k_gemm2_mfma(const float4* __restrict__ uarr,
                                                    const float* __restrict__ mom,
                                                    const float* __restrict__ W1,
                                                    const float* __restrict__ b1,
                                                    const float* __restrict__ gw,
                                                    const float* __restrict__ gb,
                                                    const float* __restrict__ gms,
                                                    const uint4* __restrict__ Bfrag,
                                                    const float* __restrict__ as2,
                                                    const float* __restrict__ ad2,
                                                    ushort* __restrict__ H2,
                                                    float* __restrict__ al_s,
                                                    float* __restrict__ al_d, int Nn) {
    __shared__ __align__(16) float4 Wc4[256];   // (w0,w1,w2,b1) per col
    __shared__ __align__(16) float2 ABs2[256];  // (A,B) per col
    __shared__ __align__(16) float4 Uld[256];   // [64 rows][4 heads]
    {
        int t = threadIdx.x;
        float w0 = W1[t], w1 = W1[256 + t], w2 = W1[512 + t], bb = b1[t];
        Wc4[t] = make_float4(w0, w1, w2, bb);
        const float* mh = mom + (t >> 6) * 9;
        float invN = 1.f / (float)Nn;
        float sw = w0 * mh[0] + w1 * mh[1] + w2 * mh[2];
        float mean = fmaf(sw, invN, bb);
        float quad = w0 * w0 * mh[3] + w1 * w1 * mh[4] + w2 * w2 * mh[5] +
                     2.f * (w0 * w1 * mh[6] + w0 * w2 * mh[7] + w1 * w2 * mh[8]);
        float E2 = fmaf(fmaf(2.f * bb, sw, quad), invN, bb * bb);
        float cm = mean * gms[t];
        float var = E2 - 2.f * cm * mean + cm * cm;
        float A = gw[t] * rsqrtf(var + GEPS);
        ABs2[t] = make_float2(A, gb[t] - A * cm);
        int row = blockIdx.x * 64 + (t >> 2);
        Uld[t] = (row < Nn) ? uarr[(size_t)row * 4 + (t & 3)] : make_float4(0.f, 0.f, 0.f, 0.f);
    }
    __syncthreads();
    int wave = threadIdx.x >> 6, lane = threadIdx.x & 63;
    int q = lane >> 4, m = lane & 15;
    int rowbase = blockIdx.x * 64 + wave * 16;
    union { short8 s; unsigned int u[4]; } af[8];
#pragma unroll
    for (int kk = 0; kk < 8; ++kk) {
        float4 u = Uld[(wave * 16 + m) * 4 + (kk >> 1)];
        int c0 = kk * 32 + q * 8;
        float vv[8];
#pragma unroll
        for (int j = 0; j < 8; ++j) {
            float4 wv = Wc4[c0 + j];
            float2 ab = ABs2[c0 + j];
            float X = fmaf(u.x, wv.x, fmaf(u.y, wv.y, fmaf(u.z, wv.z, wv.w)));
            vv[j] = elu_fast(fmaf(ab.x, X, ab.y));
        }
        af[kk].u[0] = pack_bf2(vv[0], vv[1]);
        af[kk].u[1] = pack_bf2(vv[2], vv[3]);
        af[kk].u[2] = pack_bf2(vv[4], vv[5]);
        af[kk].u[3] = pack_bf2(vv[6], vv[7]);
    }
    floatx4 acc[8];
#pragma unroll
    for (int c = 0; c < 8; ++c) acc[c] = (floatx4){0.f, 0.f, 0.f, 0.f};
#pragma unroll
    for (int kk = 0; kk < 8; ++kk) {
        const uint4* bpf = Bfrag + kk * 64 + lane;
#pragma unroll
        for (int c = 0; c < 8; ++c) {
            union { short8 s; uint4 u; } bf;
            bf.u = bpf[c * 8 * 64];
            acc[c] = __builtin_amdgcn_mfma_f32_16x16x32_bf16(af[kk].s, bf.s, acc[c], 0, 0, 0);
        }
    }
    float a_s[8], a_d[8];
#pragma unroll
    for (int c = 0; c < 8; ++c) {
        a_s[c] = as2[c * 16 + m];
        a_d[c] = ad2[c * 16 + m];
    }
#pragma unroll
    for (int r = 0; r < 4; ++r) {
        int orow = rowbase + q * 4 + r;
        bool vr = orow < Nn;
        ushort us[8];
        float s0 = 0.f, s1 = 0.f, d0 = 0.f, d1 = 0.f;
#pragma unroll
        for (int c = 0; c < 8; ++c) {
            us[c] = f2bf(acc[c][r]);
            float v = bf2f(us[c]);
            if (c < 4) {
                s0 = fmaf(v, a_s[c], s0);
                d0 = fmaf(v, a_d[c], d0);
            } else {
                s1 = fmaf(v, a_s[c], s1);
                d1 = fmaf(v, a_d[c], d1);
            }
        }
#pragma unroll
        for (int o = 1; o < 16; o <<= 1) {
            s0 += __shfl_xor(s0, o);
            s1 += __shfl_xor(s1, o);
            d0 += __shfl_xor(d0, o);
            d1 += __shfl_xor(d1, o);
        }
        if (vr) {
            ushort* op = H2 + (size_t)orow * 128 + m;
#pragma unroll
            for (int c = 0; c < 8; ++c) op[c * 16] = us[c];
            if (m == 0) {
                *(float2*)(al_s + 2 * (size_t)orow) = make_float2(s0, s1);
                *(float2*)(al_d + 2 * (size_t)orow) = make_float2(d0, d1);
            }
        }
    }
}

// ---------------- layer-2 aggregation: 16B meta + inline weights, 4-deep pipeline ------
__global__ __launch_bounds__(256) void k_agg2(const ushort* __restrict__ h2,
                                              const int* __restrict__ row_ptr,
                                              const float4* __restrict__ ed4,
                                              const float* __restrict__ al_s,
                                              const float* __restrict__ al_d,
                                              const float* __restrict__ C2,
                                              const float* __restrict__ lE,
                                              const float* __restrict__ bias,
                                              ushort* __restrict__ out, int N) {
    int n = blockIdx.x * 4 + (threadIdx.x >> 6);
    if (n >= N) return;
    int lane = threadIdx.x & 63;
    int g = lane >> 4, c16 = lane & 15;
    bool hi = c16 >= 8;
    const uint4* h2u4 = (const uint4*)h2;
    float2 ad = *(const float2*)(al_d + 2 * (size_t)n);
    float2 as = *(const float2*)(al_s + 2 * (size_t)n);
    float wsA = __expf(lrelu(as.x + ad.x + lE[0]));
    float wsB = __expf(lrelu(as.y + ad.y + lE[1]));
    float c2x = hi ? C2[1] : C2[0];
    float c2y = hi ? C2[3] : C2[2];
    float adh = hi ? ad.y : ad.x;
    uint4 hs = h2u4[(size_t)n * 16 + c16];
    float wself = (g == 0) ? (hi ? wsB : wsA) : 0.f;
    float dsum = wself;
    float acc[8];
    {
        float2 t0 = unpack_bf2(hs.x), t1 = unpack_bf2(hs.y);
        float2 t2 = unpack_bf2(hs.z), t3 = unpack_bf2(hs.w);
        acc[0] = wself * t0.x; acc[1] = wself * t0.y;
        acc[2] = wself * t1.x; acc[3] = wself * t1.y;
        acc[4] = wself * t2.x; acc[5] = wself * t2.y;
        acc[6] = wself * t3.x; acc[7] = wself * t3.y;
    }
    int i0 = row_ptr[n];
    int cnt = row_ptr[n + 1] - i0;
    if (cnt > 0) {
        int last = cnt - 1;
        int nit = (cnt + 3) >> 2;
        int j0 = g;      float mkA = 1.f; if (j0 > last) { j0 = last; mkA = 0.f; }
        int j1 = 4 + g;  float mkB = 1.f; if (j1 > last) { j1 = last; mkB = 0.f; }
        int j2 = 8 + g;  float mkC = 1.f; if (j2 > last) { j2 = last; mkC = 0.f; }
        int j3 = 12 + g; float mkD = 1.f; if (j3 > last) { j3 = last; mkD = 0.f; }
        float4 mA = ed4[i0 + j0];
        float4 mB = ed4[i0 + j1];
        float4 mC = ed4[i0 + j2];
        float4 mD = ed4[i0 + j3];
        int sA = __float_as_int(mA.x);
        float2 alA = *(const float2*)(al_s + 2 * (size_t)sA);
        uint4 gvA = h2u4[(size_t)sA * 16 + c16];
        int sB = __float_as_int(mB.x);
        float2 alB = *(const float2*)(al_s + 2 * (size_t)sB);
        uint4 gvB = h2u4[(size_t)sB * 16 + c16];
        int sC = __float_as_int(mC.x);
        float2 alC = *(const float2*)(al_s + 2 * (size_t)sC);
        uint4 gvC = h2u4[(size_t)sC * 16 + c16];
        for (int it = 0; it < nit - 1; ++it) {
            int sD = __float_as_int(mD.x);
            float2 alD = *(const float2*)(al_s + 2 * (size_t)sD);
            uint4 gvD = h2u4[(size_t)sD * 16 + c16];
            int jn = 4 * (it + 4) + g;
            float mn = 1.f;
            if (jn > last) { jn = last; mn = 0.f; }
            float4 mE = ed4[i0 + jn];
            float lg = (hi ? alA.y : alA.x) + adh + mA.y * c2x + mA.z * c2y;
            float wg = __expf(lrelu(lg)) * mkA;
            dsum += wg;
            float2 u;
            u = unpack_bf2(gvA.x); acc[0] = fmaf(wg, u.x, acc[0]); acc[1] = fmaf(wg, u.y, acc[1]);
            u = unpack_bf2(gvA.y); acc[2] = fmaf(wg, u.x, acc[2]); acc[3] = fmaf(wg, u.y, acc[3]);
            u = unpack_bf2(gvA.z); acc[4] = fmaf(wg, u.x, acc[4]); acc[5] = fmaf(wg, u.y, acc[5]);
            u = unpack_bf2(gvA.w); acc[6] = fmaf(wg, u.x, acc[6]); acc[7] = fmaf(wg, u.y, acc[7]);
            mA = mB; mB = mC; mC = mD; mD = mE;
            alA = alB; alB = alC; alC = alD;
            gvA = gvB; gvB = gvC; gvC = gvD;
            mkA = mkB; mkB = mkC; mkC = mkD; mkD = mn;
        }
        float lg = (hi ? alA.y : alA.x) + adh + mA.y * c2x + mA.z * c2y;
        float wg = __expf(lrelu(lg)) * mkA;
        dsum += wg;
        float2 u;
        u = unpack_bf2(gvA.x); acc[0] = fmaf(wg, u.x, acc[0]); acc[1] = fmaf(wg, u.y, acc[1]);
        u = unpack_bf2(gvA.y); acc[2] = fmaf(wg, u.x, acc[2]); acc[3] = fmaf(wg, u.y, acc[3]);
        u = unpack_bf2(gvA.z); acc[4] = fmaf(wg, u.x, acc[4]); acc[5] = fmaf(wg, u.y, acc[5]);
        u = unpack_bf2(gvA.w); acc[6] = fmaf(wg, u.x, acc[6]); acc[7] = fmaf(wg, u.y, acc[7]);
    }
#pragma unroll
    for (int k = 0; k < 8; ++k) {
        acc[k] += __shfl_xor(acc[k], 16);
        acc[k] += __shfl_xor(acc[k], 32);
    }
    dsum += __shfl_xor(dsum, 16);
    dsum += __shfl_xor(dsum, 32);
    if (g == 0) {
        float inv = 1.f / dsum;
        const float* bp = bias + c16 * 8;
        float4 b0 = *(const float4*)bp;
        float4 b1 = *(const float4*)(bp + 4);
        uint4 o;
        o.x = pack_bf2(fmaf(acc[0], inv, b0.x), fmaf(acc[1], inv, b0.y));
        o.y = pack_bf2(fmaf(acc[2], inv, b0.z), fmaf(acc[3], inv, b0.w));
        o.z = pack_bf2(fmaf(acc[4], inv, b1.x), fmaf(acc[5], inv, b1.y));
        o.w = pack_bf2(fmaf(acc[6], inv, b1.z), fmaf(acc[7], inv, b1.w));
        ((uint4*)out)[(size_t)n * 16 + c16] = o;
    }
}

// ---------------- GraphNorm column stats (layer-2 output only) ----------------
template <int C4>
__global__ __launch_bounds__(256) void k_stats_bf(const ushort* __restrict__ x,
                                                  float* __restrict__ stats, int rows) {
    const int C = C4 * 8;
    const int RG = 256 / C4;
    int t = threadIdx.x;
    int c = t & (C4 - 1);
    int rg = t / C4;
    int rpb = (rows + gridDim.x - 1) / gridDim.x;
    int r0 = blockIdx.x * rpb;
    int r1 = r0 + rpb;
    if (r1 > rows) r1 = rows;
    const uint4* xu = (const uint4*)x;
    float s[8] = {0.f, 0.f, 0.f, 0.f, 0.f, 0.f, 0.f, 0.f};
    float q[8] = {0.f, 0.f, 0.f, 0.f, 0.f, 0.f, 0.f, 0.f};
    for (int r = r0 + rg; r < r1; r += RG) {
        uint4 v = xu[(size_t)r * C4 + c];
        float2 a0 = unpack_bf2(v.x), a1 = unpack_bf2(v.y);
        float2 a2 = unpack_bf2(v.z), a3 = unpack_bf2(v.w);
        s[0] += a0.x; q[0] = fmaf(a0.x, a0.x, q[0]);
        s[1] += a0.y; q[1] = fmaf(a0.y, a0.y, q[1]);
        s[2] += a1.x; q[2] = fmaf(a1.x, a1.x, q[2]);
        s[3] += a1.y; q[3] = fmaf(a1.y, a1.y, q[3]);
        s[4] += a2.x; q[4] = fmaf(a2.x, a2.x, q[4]);
        s[5] += a2.y; q[5] = fmaf(a2.y, a2.y, q[5]);
        s[6] += a3.x; q[6] = fmaf(a3.x, a3.x, q[6]);
        s[7] += a3.y; q[7] = fmaf(a3.y, a3.y, q[7]);
    }
    __shared__ float ls[256 * 16];
#pragma unroll
    for (int k = 0; k < 8; ++k) {
        ls[t * 16 + k] = s[k];
        ls[t * 16 + 8 + k] = q[k];
    }
    __syncthreads();
    if (t < C) {
        int cc = t >> 3, k = t & 7;
        float ssum = 0.f, qsum = 0.f;
#pragma unroll
        for (int g = 0; g < RG; ++g) {
            ssum += ls[(g * C4 + cc) * 16 + k];
            qsum += ls[(g * C4 + cc) * 16 + 8 + k];
        }
        atomicAdd(&stats[t], ssum);
        atomicAdd(&stats[C + t], qsum);
    }
}

// ---------------- classifier: per-block coef from stats + fused GraphNorm+ELU ----------------
__global__ __launch_bounds__(256) void k_cls(const ushort* __restrict__ X,
                                             const float* __restrict__ stats,
                                             const float* __restrict__ gw,
                                             const float* __restrict__ gb,
                                             const float* __restrict__ gms,
                                             const float* __restrict__ Wc,
                                             const float* __restrict__ bc,
                                             float* __restrict__ out, int Nn) {
    __shared__ __align__(16) float ls[16 * 132];
    __shared__ __align__(16) float wT[13 * 132];
    __shared__ __align__(16) float ABs[256];
    __shared__ float bS[13];
    int t = threadIdx.x;
    int n0 = blockIdx.x * 16;
    if (t < 128) {
        float inv = 1.f / (float)Nn;
        float mean = stats[t] * inv;
        float cm = mean * gms[t];
        float var = stats[128 + t] * inv - 2.f * cm * mean + cm * cm;
        float A = gw[t] * rsqrtf(var + GEPS);
        ABs[t] = A;
        ABs[128 + t] = gb[t] - A * cm;
    }
    for (int i = t; i < 128 * 13; i += 256) {
        int k = i / 13, j = i - k * 13;
        wT[j * 132 + k] = Wc[i];
    }
    if (t < 13) bS[t] = bc[t];
    __syncthreads();
    const unsigned int* xu = (const unsigned int*)X;
    for (int idx = t; idx < 16 * 64; idx += 256) {
        int r = idx >> 6, ku = idx & 63;
        int row = n0 + r;
        float vx = 0.f, vy = 0.f;
        if (row < Nn) {
            float2 v = unpack_bf2(xu[(size_t)row * 64 + ku]);
            int k = 2 * ku;
            vx = elu_fast(fmaf(ABs[k], v.x, ABs[128 + k]));
            vy = elu_fast(fmaf(ABs[k + 1], v.y, ABs[128 + k + 1]));
        }
        ls[r * 132 + 2 * ku] = vx;
        ls[r * 132 + 2 * ku + 1] = vy;
    }
    __syncthreads();
    if (t < 208) {
        int r = t / 13, j = t - r * 13;
        int row = n0 + r;
        if (row < Nn) {
            float acc = bS[j];
            const float* lr = &ls[r * 132];
            const float* wr = &wT[j * 132];
#pragma unroll 8
            for (int k = 0; k < 128; k += 4) {
                float4 a = *(const float4*)&lr[k];
                float4 b = *(const float4*)&wr[k];
                acc = fmaf(a.x, b.x, fmaf(a.y, b.y, fmaf(a.z, b.z, fmaf(a.w, b.w, acc))));
            }
            out[(size_t)row * 13 + j] = acc;
        }
    }
}

extern "C" void kernel_launch(void* const* d_in, const int* in_sizes, int n_in, void* d_out,
                              int out_size, void* d_ws, size_t ws_size, hipStream_t stream) {
    const float* x = (const float*)d_in[0];
    const int* edge_index = (const int*)d_in[1];
    const float* edge_attr = (const float*)d_in[2];
    const float* W1 = (const float*)d_in[3];
    const float* We1 = (const float*)d_in[4];
    const float* as1 = (const float*)d_in[5];
    const float* ad1 = (const float*)d_in[6];
    const float* ae1 = (const float*)d_in[7];
    const float* b1 = (const float*)d_in[8];
    const float* gn1_w = (const float*)d_in[9];
    const float* gn1_b = (const float*)d_in[10];
    const float* gn1_ms = (const float*)d_in[11];
    const float* W2 = (const float*)d_in[12];
    const float* We2 = (const float*)d_in[13];
    const float* as2 = (const float*)d_in[14];
    const float* ad2 = (const float*)d_in[15];
    const float* ae2 = (const float*)d_in[16];
    const float* b2 = (const float*)d_in[17];
    const float* gn2_w = (const float*)d_in[18];
    const float* gn2_b = (const float*)d_in[19];
    const float* gn2_ms = (const float*)d_in[20];
    const float* Wc = (const float*)d_in[21];
    const float* bc = (const float*)d_in[22];

    const int N = in_sizes[0] / 3;
    const int E = in_sizes[1] / 2;
    const int* srcv = edge_index;
    const int* dstv = edge_index + E;

    // ---- workspace carve (256B-aligned, byte-based) ----
    char* w = (char*)d_ws;
    auto carveB = [&](size_t bytes) -> void* {
        void* p = (void*)w;
        w += ((bytes + 255) / 256) * 256;
        return p;
    };
    // zeroed region first:
    int* deg = (int*)carveB((size_t)N * 4);
    float* ea_sum = (float*)carveB(8);
    float* mom = (float*)carveB(36 * 4);
    float* statsB = (float*)carveB(256 * 4);
    char* zero_end = w;
    // not zeroed:
    int* row_ptr = (int*)carveB((size_t)(N + 1) * 4);
    float4* ed4 = (float4*)carveB((size_t)E * 16);
    float* C1 = (float*)carveB(8 * 4);
    float* C2 = (float*)carveB(4 * 4);
    float* Ps = (float*)carveB(12 * 4);
    float* Pd = (float*)carveB(12 * 4);
    float* lE1 = (float*)carveB(4 * 4);
    float* lE2 = (float*)carveB(2 * 4);
    uint4* Bfrag = (uint4*)carveB(4096 * 16);
    float4* ndr = (float4*)carveB((size_t)N * 32);        // {x0,x1,x2,_}|{as1(4)} per node
    float* al_d1 = (float*)carveB((size_t)N * 4 * 4);
    float* al_s2 = (float*)carveB((size_t)N * 2 * 4);
    float* al_d2 = (float*)carveB((size_t)N * 2 * 4);
    float4* uarr = (float4*)carveB((size_t)N * 4 * 16);   // per-node per-head u
    ushort* h2b = (ushort*)carveB((size_t)N * 128 * 2);   // bf16 h2
    ushort* out2b = (ushort*)carveB((size_t)N * 128 * 2); // bf16 layer-2 output

    hipMemsetAsync(deg, 0, (size_t)(zero_end - (char*)deg), stream);

    const int nb1 = (N + 1023) / 1024;
    const int ebl = (E + 255) / 256;

    k_pre<<<17 + 256, 256, 0, stream>>>(W1, as1, ad1, edge_attr, dstv, W2, We1, ae1, We2, ae2,
                                        ea_sum, deg, Bfrag, C1, C2, Ps, Pd, E);
    k_scan<<<nb1, 1024, 0, stream>>>(deg, row_ptr, ea_sum, C1, C2, Ps, Pd, x, ndr, al_d1,
                                     lE1, lE2, N, E);
    k_scat<<<ebl, 256, 0, stream>>>(dstv, srcv, edge_attr, row_ptr, deg, ed4, E);
    k_agg1<<<(N + 7) / 8, 256, 0, stream>>>(ndr, row_ptr, ed4, al_d1, C1, lE1, uarr, N);
    k_mom<<<128, 256, 0, stream>>>(uarr, mom, N * 4);
    k_gemm2_mfma<<<(N + 63) / 64, 256, 0, stream>>>(uarr, mom, W1, b1, gn1_w, gn1_b, gn1_ms,
                                                    Bfrag, as2, ad2, h2b, al_s2, al_d2, N);
    k_agg2<<<(N + 3) / 4, 256, 0, stream>>>(h2b, row_ptr, ed4, al_s2, al_d2, C2, lE2, b2,
                                            out2b, N);
    k_stats_bf<16><<<256, 256, 0, stream>>>(out2b, statsB, N);
    k_cls<<<(N + 15) / 16, 256, 0, stream>>>(out2b, statsB, gn2_w, gn2_b, gn2_ms, Wc, bc,
                                             (float*)d_out, N);
}

// Round 12
// 268.058 us; speedup vs baseline: 1.0244x; 1.0244x over previous
//
#include <hip/hip_runtime.h>
#include <math.h>

#define NEG_SLOPE 0.2f
#define GEPS 1e-5f

typedef __attribute__((ext_vector_type(8))) short short8;
typedef __attribute__((ext_vector_type(4))) float floatx4;

__device__ __forceinline__ float wave_reduce_sum(float v) {
#pragma unroll
    for (int o = 32; o > 0; o >>= 1) v += __shfl_down(v, o);
    return v;
}

__device__ __forceinline__ ushort f2bf(float f) {
    union { float f; unsigned int i; } c;
    c.f = f;
    unsigned int b = c.i;
    b += 0x7fffu + ((b >> 16) & 1u);
    return (ushort)(b >> 16);
}

__device__ __forceinline__ float bf2f(ushort u) {
    union { unsigned int i; float f; } c;
    c.i = (unsigned int)u << 16;
    return c.f;
}

__device__ __forceinline__ float2 unpack_bf2(unsigned int u) {
    union { unsigned int i; float f; } a, b;
    a.i = u << 16;            // low ushort -> even col
    b.i = u & 0xffff0000u;    // high ushort -> odd col
    return make_float2(a.f, b.f);
}

__device__ __forceinline__ unsigned int pack_bf2(float lo, float hi) {
    return (unsigned int)f2bf(lo) | ((unsigned int)f2bf(hi) << 16);
}

__device__ __forceinline__ float lrelu(float v) {
    return (v > 0.f) ? v : v * NEG_SLOPE;
}

__device__ __forceinline__ float elu_fast(float v) {
    return (v > 0.f) ? v : (__expf(v) - 1.f);
}

// ---------------- merged prologue ----------------
// blocks [0, 16)   : W2 -> bf16 MFMA B-fragment layout
// block  16        : attn consts: C1 (We1.ae1), C2 (We2.ae2), P_s1/P_d1 (W1@as1 / W1@ad1, 3/head)
// blocks [17, 273) : edge_attr column sums + degree histogram
__global__ __launch_bounds__(256) void k_pre(
    const float* __restrict__ W1, const float* __restrict__ as1, const float* __restrict__ ad1,
    const float* __restrict__ ea, const int* __restrict__ dst,
    const float* __restrict__ W2, const float* __restrict__ We1,
    const float* __restrict__ ae1, const float* __restrict__ We2,
    const float* __restrict__ ae2,
    float* __restrict__ ea_sum, int* __restrict__ deg, uint4* __restrict__ Bfrag,
    float* __restrict__ C1, float* __restrict__ C2, float* __restrict__ Ps,
    float* __restrict__ Pd, int E) {
    int b = blockIdx.x;
    if (b < 16) {
        int t = b * 256 + threadIdx.x;  // 4096 threads
        int c = t >> 9, kk = (t >> 6) & 7, L = t & 63;
        int q = L >> 4, n = c * 16 + (L & 15);
        int k0 = kk * 32 + q * 8;
        unsigned int u0 = pack_bf2(W2[(k0 + 0) * 128 + n], W2[(k0 + 1) * 128 + n]);
        unsigned int u1 = pack_bf2(W2[(k0 + 2) * 128 + n], W2[(k0 + 3) * 128 + n]);
        unsigned int u2 = pack_bf2(W2[(k0 + 4) * 128 + n], W2[(k0 + 5) * 128 + n]);
        unsigned int u3 = pack_bf2(W2[(k0 + 6) * 128 + n], W2[(k0 + 7) * 128 + n]);
        Bfrag[t] = make_uint4(u0, u1, u2, u3);
        return;
    }
    if (b == 16) {
        int t = threadIdx.x, h = t >> 6, lane = t & 63;
        float p0 = We1[t] * ae1[t];
        float p1 = We1[256 + t] * ae1[t];
        p0 = wave_reduce_sum(p0);
        p1 = wave_reduce_sum(p1);
        if (lane == 0) { C1[h] = p0; C1[4 + h] = p1; }
        float av = as1[t], dv = ad1[t];
#pragma unroll
        for (int k = 0; k < 3; ++k) {
            float wv = W1[k * 256 + t];
            float ps = wave_reduce_sum(wv * av);
            float pd = wave_reduce_sum(wv * dv);
            if (lane == 0) { Ps[h * 3 + k] = ps; Pd[h * 3 + k] = pd; }
        }
        if (t < 128) {
            float q0 = We2[t] * ae2[t];
            float q1 = We2[128 + t] * ae2[t];
            q0 = wave_reduce_sum(q0);
            q1 = wave_reduce_sum(q1);
            if (lane == 0) { C2[h] = q0; C2[2 + h] = q1; }
        }
        return;
    }
    b -= 17;
    const float2* ea2 = (const float2*)ea;
    float s0 = 0.f, s1 = 0.f;
    for (int e = b * 256 + threadIdx.x; e < E; e += 256 * 256) {
        float2 v = ea2[e];
        s0 += v.x; s1 += v.y;
        atomicAdd(&deg[dst[e]], 1);
    }
    s0 = wave_reduce_sum(s0);
    s1 = wave_reduce_sum(s1);
    if ((threadIdx.x & 63) == 0) {
        atomicAdd(&ea_sum[0], s0);
        atomicAdd(&ea_sum[1], s1);
    }
}

// ---------------- CSR row_ptr scan (block-local) ----------------
__global__ void k_scan1(const int* __restrict__ deg, int* __restrict__ row_ptr,
                        int* __restrict__ bsum, int N) {
    __shared__ int tmp[1024];
    int tid = threadIdx.x;
    int i = blockIdx.x * 1024 + tid;
    int v = (i < N) ? deg[i] : 0;
    tmp[tid] = v;
    __syncthreads();
#pragma unroll
    for (int off = 1; off < 1024; off <<= 1) {
        int t = (tid >= off) ? tmp[tid - off] : 0;
        __syncthreads();
        tmp[tid] += t;
        __syncthreads();
    }
    if (i < N) row_ptr[i + 1] = tmp[tid];
    if (tid == 1023) bsum[blockIdx.x] = tmp[1023];
}

// block prefix recomputed per block in one wave (nb1 <= 64), then applied.
// also: lE1/lE2 self-loop consts, node record ndr = {x(3),_, as1(4)}, and al_d1 fill.
__global__ void k_scan23(int* __restrict__ row_ptr, const int* __restrict__ bsum,
                         const float* __restrict__ ea_sum, const float* __restrict__ C1,
                         const float* __restrict__ C2, const float* __restrict__ Ps,
                         const float* __restrict__ Pd, const float* __restrict__ x,
                         float4* __restrict__ ndr, float* __restrict__ al_d1,
                         float* __restrict__ lE1, float* __restrict__ lE2, int N, int E) {
    __shared__ int off_s;
    int t = threadIdx.x;
    if (blockIdx.x == 0 && t >= 64 && t < 68) {
        int k = t - 64;
        float m0 = ea_sum[0] / (float)E, m1 = ea_sum[1] / (float)E;
        lE1[k] = m0 * C1[k] + m1 * C1[4 + k];
        if (k < 2) lE2[k] = m0 * C2[k] + m1 * C2[2 + k];
    }
    if (t < 64) {
        int v = (t < blockIdx.x) ? bsum[t] : 0;
#pragma unroll
        for (int o = 32; o > 0; o >>= 1) v += __shfl_xor(v, o);
        if (t == 0) off_s = v;
    }
    __syncthreads();
    int off = off_s;
    int i = blockIdx.x * 1024 + t;
    if (i == 0) row_ptr[0] = 0;
    if (i < N) {
        row_ptr[i + 1] += off;
        float x0 = x[3 * i], x1 = x[3 * i + 1], x2 = x[3 * i + 2];
        float4 sv, dv;
        sv.x = fmaf(x0, Ps[0], fmaf(x1, Ps[1], x2 * Ps[2]));
        sv.y = fmaf(x0, Ps[3], fmaf(x1, Ps[4], x2 * Ps[5]));
        sv.z = fmaf(x0, Ps[6], fmaf(x1, Ps[7], x2 * Ps[8]));
        sv.w = fmaf(x0, Ps[9], fmaf(x1, Ps[10], x2 * Ps[11]));
        dv.x = fmaf(x0, Pd[0], fmaf(x1, Pd[1], x2 * Pd[2]));
        dv.y = fmaf(x0, Pd[3], fmaf(x1, Pd[4], x2 * Pd[5]));
        dv.z = fmaf(x0, Pd[6], fmaf(x1, Pd[7], x2 * Pd[8]));
        dv.w = fmaf(x0, Pd[9], fmaf(x1, Pd[10], x2 * Pd[11]));
        ndr[2 * (size_t)i] = make_float4(x0, x1, x2, 0.f);
        ndr[2 * (size_t)i + 1] = sv;
        *(float4*)(al_d1 + 4 * (size_t)i) = dv;
    }
}

// ---------------- CSR scatter: pure 16B record {src, ea.x, ea.y} ----------------
__global__ void k_scat(const int* __restrict__ dst, const int* __restrict__ src,
                       const float* __restrict__ ea, const int* __restrict__ row_ptr,
                       int* __restrict__ deg, float4* __restrict__ ed4, int E) {
    int e = blockIdx.x * 256 + threadIdx.x;
    if (e >= E) return;
    int d = dst[e];
    int r = atomicSub(&deg[d], 1);
    int slot = row_ptr[d] + r - 1;
    float2 v = ((const float2*)ea)[e];
    ed4[slot] = make_float4(__int_as_float(src[e]), v.x, v.y, 0.f);
}

// ---------------- layer-1 aggregation in x-space: 16 lanes/node, inline weights --------
// mean degree 8 -> 16 lanes cover the row in one pass (P(deg>16) ~ 0.2%).
// 4-stage reduce-scatter (15 shuffles): lane l ends with head h=l>>2, component c=l&3
// (c: 0..2 = z, 3 = dsum). One shfl broadcasts dsum; 12 scalar stores per node.
__global__ __launch_bounds__(256) void k_agg1(const float4* __restrict__ ndr,
                                              const int* __restrict__ row_ptr,
                                              const float4* __restrict__ ed4,
                                              const float* __restrict__ al_d,
                                              const float* __restrict__ C1,
                                              const float* __restrict__ lE,
                                              float* __restrict__ uarr_f, int N) {
    int l = threadIdx.x & 15;
    int grp = threadIdx.x >> 4;  // 16 node-groups per block
    int n = blockIdx.x * 16 + grp;
    if (n >= N) return;
    float4 adn = *(const float4*)(al_d + 4 * (size_t)n);
    float4 c1a = *(const float4*)C1;       // ea.x coef per head
    float4 c1b = *(const float4*)(C1 + 4); // ea.y coef per head
    float4 le = *(const float4*)lE;
    float4 ndx = ndr[2 * (size_t)n];       // own x
    float4 nas = ndr[2 * (size_t)n + 1];   // own al_s
    float z[12];
    float ds[4];
#pragma unroll
    for (int k = 0; k < 12; ++k) z[k] = 0.f;
#pragma unroll
    for (int k = 0; k < 4; ++k) ds[k] = 0.f;
    int i0 = row_ptr[n];
    int cnt = row_ptr[n + 1] - i0;
    for (int j = l; j < cnt; j += 16) {
        float4 m = ed4[i0 + j];
        int s = __float_as_int(m.x);
        float4 xr = ndr[2 * (size_t)s];
        float4 as = ndr[2 * (size_t)s + 1];
        float w0 = __expf(lrelu(as.x + adn.x + m.y * c1a.x + m.z * c1b.x));
        float w1 = __expf(lrelu(as.y + adn.y + m.y * c1a.y + m.z * c1b.y));
        float w2 = __expf(lrelu(as.z + adn.z + m.y * c1a.z + m.z * c1b.z));
        float w3 = __expf(lrelu(as.w + adn.w + m.y * c1a.w + m.z * c1b.w));
        z[0] = fmaf(w0, xr.x, z[0]); z[1] = fmaf(w0, xr.y, z[1]); z[2] = fmaf(w0, xr.z, z[2]);
        z[3] = fmaf(w1, xr.x, z[3]); z[4] = fmaf(w1, xr.y, z[4]); z[5] = fmaf(w1, xr.z, z[5]);
        z[6] = fmaf(w2, xr.x, z[6]); z[7] = fmaf(w2, xr.y, z[7]); z[8] = fmaf(w2, xr.z, z[8]);
        z[9] = fmaf(w3, xr.x, z[9]); z[10] = fmaf(w3, xr.y, z[10]); z[11] = fmaf(w3, xr.z, z[11]);
        ds[0] += w0; ds[1] += w1; ds[2] += w2; ds[3] += w3;
    }
    float gv, rv;
    // stage 1 (xor 8): keep head pair {0,1} if !(l&8) else {2,3}
    bool b8 = (l & 8) != 0;
    float a00, a01, a02, a03, a10, a11, a12, a13;
    gv = b8 ? z[0] : z[6];   rv = __shfl_xor(gv, 8); a00 = (b8 ? z[6] : z[0]) + rv;
    gv = b8 ? z[1] : z[7];   rv = __shfl_xor(gv, 8); a01 = (b8 ? z[7] : z[1]) + rv;
    gv = b8 ? z[2] : z[8];   rv = __shfl_xor(gv, 8); a02 = (b8 ? z[8] : z[2]) + rv;
    gv = b8 ? ds[0] : ds[2]; rv = __shfl_xor(gv, 8); a03 = (b8 ? ds[2] : ds[0]) + rv;
    gv = b8 ? z[3] : z[9];   rv = __shfl_xor(gv, 8); a10 = (b8 ? z[9] : z[3]) + rv;
    gv = b8 ? z[4] : z[10];  rv = __shfl_xor(gv, 8); a11 = (b8 ? z[10] : z[4]) + rv;
    gv = b8 ? z[5] : z[11];  rv = __shfl_xor(gv, 8); a12 = (b8 ? z[11] : z[5]) + rv;
    gv = b8 ? ds[1] : ds[3]; rv = __shfl_xor(gv, 8); a13 = (b8 ? ds[3] : ds[1]) + rv;
    // stage 2 (xor 4): keep own head within the pair
    bool b4 = (l & 4) != 0;
    float e0, e1, e2, e3;
    gv = b4 ? a00 : a10; rv = __shfl_xor(gv, 4); e0 = (b4 ? a10 : a00) + rv;
    gv = b4 ? a01 : a11; rv = __shfl_xor(gv, 4); e1 = (b4 ? a11 : a01) + rv;
    gv = b4 ? a02 : a12; rv = __shfl_xor(gv, 4); e2 = (b4 ? a12 : a02) + rv;
    gv = b4 ? a03 : a13; rv = __shfl_xor(gv, 4); e3 = (b4 ? a13 : a03) + rv;
    // stage 3 (xor 2): keep component pair {z0,z1} if !(l&2) else {z2,ds}
    bool b2 = (l & 2) != 0;
    float d0, d1;
    gv = b2 ? e0 : e2; rv = __shfl_xor(gv, 2); d0 = (b2 ? e2 : e0) + rv;
    gv = b2 ? e1 : e3; rv = __shfl_xor(gv, 2); d1 = (b2 ? e3 : e1) + rv;
    // stage 4 (xor 1): keep one component
    bool b1v = (l & 1) != 0;
    gv = b1v ? d0 : d1; rv = __shfl_xor(gv, 1);
    float val = (b1v ? d1 : d0) + rv;
    // lane l now holds sum for head h = l>>2, component c = l&3 (c==3 -> dsum)
    int h = l >> 2, c = l & 3;
    float nash = (h == 0) ? nas.x : (h == 1) ? nas.y : (h == 2) ? nas.z : nas.w;
    float adnh = (h == 0) ? adn.x : (h == 1) ? adn.y : (h == 2) ? adn.z : adn.w;
    float leh = (h == 0) ? le.x : (h == 1) ? le.y : (h == 2) ? le.z : le.w;
    float wsh = __expf(lrelu(nash + adnh + leh));
    float xc = (c == 0) ? ndx.x : (c == 1) ? ndx.y : (c == 2) ? ndx.z : 1.f;
    val = fmaf(wsh, xc, val);
    int wl = threadIdx.x & 63;
    float dsv = __shfl(val, wl | 3);  // c==3 lane of this head (same 4-lane cluster)
    if (c < 3) {
        uarr_f[(size_t)n * 16 + h * 4 + c] = val * (1.f / dsv);
    }
}

// ---------------- per-head moments of u: Su(3) + Suu^T(6) -> 36 floats ----------------
__global__ __launch_bounds__(256) void k_mom(const float4* __restrict__ uarr,
                                             float* __restrict__ mom, int N4) {
    int t = threadIdx.x;
    float m[9] = {0.f, 0.f, 0.f, 0.f, 0.f, 0.f, 0.f, 0.f, 0.f};
    for (int i = blockIdx.x * 256 + t; i < N4; i += gridDim.x * 256) {
        float4 u = uarr[i];
        m[0] += u.x; m[1] += u.y; m[2] += u.z;
        m[3] = fmaf(u.x, u.x, m[3]);
        m[4] = fmaf(u.y, u.y, m[4]);
        m[5] = fmaf(u.z, u.z, m[5]);
        m[6] = fmaf(u.x, u.y, m[6]);
        m[7] = fmaf(u.x, u.z, m[7]);
        m[8] = fmaf(u.y, u.z, m[8]);
    }
    __shared__ float ls[256 * 9];
#pragma unroll
    for (int k = 0; k < 9; ++k) ls[t * 9 + k] = m[k];
    __syncthreads();
    if (t < 36) {
        int h = t / 9, k = t - h * 9;
        float s = 0.f;
        for (int tt = h; tt < 256; tt += 4) s += ls[tt * 9 + k];
        atomicAdd(&mom[t], s);
    }
}

// ---------------- MFMA GEMM2: expand out1 from uarr + analytic GraphNorm coefs ----------
__global__ __launch_bounds__(256) void k_gemm2_mfma(const float4* __restrict__ uarr,
                                                    const float* __restrict__ mom,
                                                    const float* __restrict__ W1,
                                                    const float* __restrict__ b1,
                                                    const float* __restrict__ gw,
                                                    const float* __restrict__ gb,
                                                    const float* __restrict__ gms,
                                                    const uint4* __restrict__ Bfrag,
                                                    const float* __restrict__ as2,
                                                    const float* __restrict__ ad2,
                                                    ushort* __restrict__ H2,
                                                    float* __restrict__ al_s,
                                                    float* __restrict__ al_d, int Nn) {
    __shared__ __align__(16) float4 Wc4[256];   // (w0,w1,w2,b1) per col
    __shared__ __align__(16) float2 ABs2[256];  // (A,B) per col
    __shared__ __align__(16) float4 Uld[256];   // [64 rows][4 heads]
    {
        int t = threadIdx.x;
        float w0 = W1[t], w1 = W1[256 + t], w2 = W1[512 + t], bb = b1[t];
        Wc4[t] = make_float4(w0, w1, w2, bb);
        const float* mh = mom + (t >> 6) * 9;
        float invN = 1.f / (float)Nn;
        float sw = w0 * mh[0] + w1 * mh[1] + w2 * mh[2];
        float mean = fmaf(sw, invN, bb);
        float quad = w0 * w0 * mh[3] + w1 * w1 * mh[4] + w2 * w2 * mh[5] +
                     2.f * (w0 * w1 * mh[6] + w0 * w2 * mh[7] + w1 * w2 * mh[8]);
        float E2 = fmaf(fmaf(2.f * bb, sw, quad), invN, bb * bb);
        float cm = mean * gms[t];
        float var = E2 - 2.f * cm * mean + cm * cm;
        float A = gw[t] * rsqrtf(var + GEPS);
        ABs2[t] = make_float2(A, gb[t] - A * cm);
        int row = blockIdx.x * 64 + (t >> 2);
        Uld[t] = (row < Nn) ? uarr[(size_t)row * 4 + (t & 3)] : make_float4(0.f, 0.f, 0.f, 0.f);
    }
    __syncthreads();
    int wave = threadIdx.x >> 6, lane = threadIdx.x & 63;
    int q = lane >> 4, m = lane & 15;
    int rowbase = blockIdx.x * 64 + wave * 16;
    union { short8 s; unsigned int u[4]; } af[8];
#pragma unroll
    for (int kk = 0; kk < 8; ++kk) {
        float4 u = Uld[(wave * 16 + m) * 4 + (kk >> 1)];
        int c0 = kk * 32 + q * 8;
        float vv[8];
#pragma unroll
        for (int j = 0; j < 8; ++j) {
            float4 wv = Wc4[c0 + j];
            float2 ab = ABs2[c0 + j];
            float X = fmaf(u.x, wv.x, fmaf(u.y, wv.y, fmaf(u.z, wv.z, wv.w)));
            vv[j] = elu_fast(fmaf(ab.x, X, ab.y));
        }
        af[kk].u[0] = pack_bf2(vv[0], vv[1]);
        af[kk].u[1] = pack_bf2(vv[2], vv[3]);
        af[kk].u[2] = pack_bf2(vv[4], vv[5]);
        af[kk].u[3] = pack_bf2(vv[6], vv[7]);
    }
    floatx4 acc[8];
#pragma unroll
    for (int c = 0; c < 8; ++c) acc[c] = (floatx4){0.f, 0.f, 0.f, 0.f};
#pragma unroll
    for (int kk = 0; kk < 8; ++kk) {
        const uint4* bpf = Bfrag + kk * 64 + lane;
#pragma unroll
        for (int c = 0; c < 8; ++c) {
            union { short8 s; uint4 u; } bf;
            bf.u = bpf[c * 8 * 64];
            acc[c] = __builtin_amdgcn_mfma_f32_16x16x32_bf16(af[kk].s, bf.s, acc[c], 0, 0, 0);
        }
    }
    float a_s[8], a_d[8];
#pragma unroll
    for (int c = 0; c < 8; ++c) {
        a_s[c] = as2[c * 16 + m];
        a_d[c] = ad2[c * 16 + m];
    }
#pragma unroll
    for (int r = 0; r < 4; ++r) {
        int orow = rowbase + q * 4 + r;
        bool vr = orow < Nn;
        ushort us[8];
        float s0 = 0.f, s1 = 0.f, d0 = 0.f, d1 = 0.f;
#pragma unroll
        for (int c = 0; c < 8; ++c) {
            us[c] = f2bf(acc[c][r]);
            float v = bf2f(us[c]);
            if (c < 4) {
                s0 = fmaf(v, a_s[c], s0);
                d0 = fmaf(v, a_d[c], d0);
            } else {
                s1 = fmaf(v, a_s[c], s1);
                d1 = fmaf(v, a_d[c], d1);
            }
        }
#pragma unroll
        for (int o = 1; o < 16; o <<= 1) {
            s0 += __shfl_xor(s0, o);
            s1 += __shfl_xor(s1, o);
            d0 += __shfl_xor(d0, o);
            d1 += __shfl_xor(d1, o);
        }
        if (vr) {
            ushort* op = H2 + (size_t)orow * 128 + m;
#pragma unroll
            for (int c = 0; c < 8; ++c) op[c * 16] = us[c];
            if (m == 0) {
                *(float2*)(al_s + 2 * (size_t)orow) = make_float2(s0, s1);
                *(float2*)(al_d + 2 * (size_t)orow) = make_float2(d0, d1);
            }
        }
    }
}

// ---------------- layer-2 aggregation: 16B meta + inline weights, 4-deep pipeline ------
__global__ __launch_bounds__(256) void k_agg2(const ushort* __restrict__ h2,
                                              const int* __restrict__ row_ptr,
                                              const float4* __restrict__ ed4,
                                              const float* __restrict__ al_s,
                                              const float* __restrict__ al_d,
                                              const float* __restrict__ C2,
                                              const float* __restrict__ lE,
                                              const float* __restrict__ bias,
                                              ushort* __restrict__ out, int N) {
    int n = blockIdx.x * 4 + (threadIdx.x >> 6);
    if (n >= N) return;
    int lane = threadIdx.x & 63;
    int g = lane >> 4, c16 = lane & 15;
    bool hi = c16 >= 8;
    const uint4* h2u4 = (const uint4*)h2;
    float2 ad = *(const float2*)(al_d + 2 * (size_t)n);
    float2 as = *(const float2*)(al_s + 2 * (size_t)n);
    float wsA = __expf(lrelu(as.x + ad.x + lE[0]));
    float wsB = __expf(lrelu(as.y + ad.y + lE[1]));
    float c2x = hi ? C2[1] : C2[0];
    float c2y = hi ? C2[3] : C2[2];
    float adh = hi ? ad.y : ad.x;
    uint4 hs = h2u4[(size_t)n * 16 + c16];
    float wself = (g == 0) ? (hi ? wsB : wsA) : 0.f;
    float dsum = wself;
    float acc[8];
    {
        float2 t0 = unpack_bf2(hs.x), t1 = unpack_bf2(hs.y);
        float2 t2 = unpack_bf2(hs.z), t3 = unpack_bf2(hs.w);
        acc[0] = wself * t0.x; acc[1] = wself * t0.y;
        acc[2] = wself * t1.x; acc[3] = wself * t1.y;
        acc[4] = wself * t2.x; acc[5] = wself * t2.y;
        acc[6] = wself * t3.x; acc[7] = wself * t3.y;
    }
    int i0 = row_ptr[n];
    int cnt = row_ptr[n + 1] - i0;
    if (cnt > 0) {
        int last = cnt - 1;
        int nit = (cnt + 3) >> 2;
        int j0 = g;      float mkA = 1.f; if (j0 > last) { j0 = last; mkA = 0.f; }
        int j1 = 4 + g;  float mkB = 1.f; if (j1 > last) { j1 = last; mkB = 0.f; }
        int j2 = 8 + g;  float mkC = 1.f; if (j2 > last) { j2 = last; mkC = 0.f; }
        int j3 = 12 + g; float mkD = 1.f; if (j3 > last) { j3 = last; mkD = 0.f; }
        float4 mA = ed4[i0 + j0];
        float4 mB = ed4[i0 + j1];
        float4 mC = ed4[i0 + j2];
        float4 mD = ed4[i0 + j3];
        int sA = __float_as_int(mA.x);
        float2 alA = *(const float2*)(al_s + 2 * (size_t)sA);
        uint4 gvA = h2u4[(size_t)sA * 16 + c16];
        int sB = __float_as_int(mB.x);
        float2 alB = *(const float2*)(al_s + 2 * (size_t)sB);
        uint4 gvB = h2u4[(size_t)sB * 16 + c16];
        int sC = __float_as_int(mC.x);
        float2 alC = *(const float2*)(al_s + 2 * (size_t)sC);
        uint4 gvC = h2u4[(size_t)sC * 16 + c16];
        for (int it = 0; it < nit - 1; ++it) {
            int sD = __float_as_int(mD.x);
            float2 alD = *(const float2*)(al_s + 2 * (size_t)sD);
            uint4 gvD = h2u4[(size_t)sD * 16 + c16];
            int jn = 4 * (it + 4) + g;
            float mn = 1.f;
            if (jn > last) { jn = last; mn = 0.f; }
            float4 mE = ed4[i0 + jn];
            float lg = (hi ? alA.y : alA.x) + adh + mA.y * c2x + mA.z * c2y;
            float wg = __expf(lrelu(lg)) * mkA;
            dsum += wg;
            float2 u;
            u = unpack_bf2(gvA.x); acc[0] = fmaf(wg, u.x, acc[0]); acc[1] = fmaf(wg, u.y, acc[1]);
            u = unpack_bf2(gvA.y); acc[2] = fmaf(wg, u.x, acc[2]); acc[3] = fmaf(wg, u.y, acc[3]);
            u = unpack_bf2(gvA.z); acc[4] = fmaf(wg, u.x, acc[4]); acc[5] = fmaf(wg, u.y, acc[5]);
            u = unpack_bf2(gvA.w); acc[6] = fmaf(wg, u.x, acc[6]); acc[7] = fmaf(wg, u.y, acc[7]);
            mA = mB; mB = mC; mC = mD; mD = mE;
            alA = alB; alB = alC; alC = alD;
            gvA = gvB; gvB = gvC; gvC = gvD;
            mkA = mkB; mkB = mkC; mkC = mkD; mkD = mn;
        }
        float lg = (hi ? alA.y : alA.x) + adh + mA.y * c2x + mA.z * c2y;
        float wg = __expf(lrelu(lg)) * mkA;
        dsum += wg;
        float2 u;
        u = unpack_bf2(gvA.x); acc[0] = fmaf(wg, u.x, acc[0]); acc[1] = fmaf(wg, u.y, acc[1]);
        u = unpack_bf2(gvA.y); acc[2] = fmaf(wg, u.x, acc[2]); acc[3] = fmaf(wg, u.y, acc[3]);
        u = unpack_bf2(gvA.z); acc[4] = fmaf(wg, u.x, acc[4]); acc[5] = fmaf(wg, u.y, acc[5]);
        u = unpack_bf2(gvA.w); acc[6] = fmaf(wg, u.x, acc[6]); acc[7] = fmaf(wg, u.y, acc[7]);
    }
#pragma unroll
    for (int k = 0; k < 8; ++k) {
        acc[k] += __shfl_xor(acc[k], 16);
        acc[k] += __shfl_xor(acc[k], 32);
    }
    dsum += __shfl_xor(dsum, 16);
    dsum += __shfl_xor(dsum, 32);
    if (g == 0) {
        float inv = 1.f / dsum;
        const float* bp = bias + c16 * 8;
        float4 b0 = *(const float4*)bp;
        float4 b1 = *(const float4*)(bp + 4);
        uint4 o;
        o.x = pack_bf2(fmaf(acc[0], inv, b0.x), fmaf(acc[1], inv, b0.y));
        o.y = pack_bf2(fmaf(acc[2], inv, b0.z), fmaf(acc[3], inv, b0.w));
        o.z = pack_bf2(fmaf(acc[4], inv, b1.x), fmaf(acc[5], inv, b1.y));
        o.w = pack_bf2(fmaf(acc[6], inv, b1.z), fmaf(acc[7], inv, b1.w));
        ((uint4*)out)[(size_t)n * 16 + c16] = o;
    }
}

// ---------------- GraphNorm column stats (layer-2 output only) ----------------
template <int C4>
__global__ __launch_bounds__(256) void k_stats_bf(const ushort* __restrict__ x,
                                                  float* __restrict__ stats, int rows) {
    const int C = C4 * 8;
    const int RG = 256 / C4;
    int t = threadIdx.x;
    int c = t & (C4 - 1);
    int rg = t / C4;
    int rpb = (rows + gridDim.x - 1) / gridDim.x;
    int r0 = blockIdx.x * rpb;
    int r1 = r0 + rpb;
    if (r1 > rows) r1 = rows;
    const uint4* xu = (const uint4*)x;
    float s[8] = {0.f, 0.f, 0.f, 0.f, 0.f, 0.f, 0.f, 0.f};
    float q[8] = {0.f, 0.f, 0.f, 0.f, 0.f, 0.f, 0.f, 0.f};
    for (int r = r0 + rg; r < r1; r += RG) {
        uint4 v = xu[(size_t)r * C4 + c];
        float2 a0 = unpack_bf2(v.x), a1 = unpack_bf2(v.y);
        float2 a2 = unpack_bf2(v.z), a3 = unpack_bf2(v.w);
        s[0] += a0.x; q[0] = fmaf(a0.x, a0.x, q[0]);
        s[1] += a0.y; q[1] = fmaf(a0.y, a0.y, q[1]);
        s[2] += a1.x; q[2] = fmaf(a1.x, a1.x, q[2]);
        s[3] += a1.y; q[3] = fmaf(a1.y, a1.y, q[3]);
        s[4] += a2.x; q[4] = fmaf(a2.x, a2.x, q[4]);
        s[5] += a2.y; q[5] = fmaf(a2.y, a2.y, q[5]);
        s[6] += a3.x; q[6] = fmaf(a3.x, a3.x, q[6]);
        s[7] += a3.y; q[7] = fmaf(a3.y, a3.y, q[7]);
    }
    __shared__ float ls[256 * 16];
#pragma unroll
    for (int k = 0; k < 8; ++k) {
        ls[t * 16 + k] = s[k];
        ls[t * 16 + 8 + k] = q[k];
    }
    __syncthreads();
    if (t < C) {
        int cc = t >> 3, k = t & 7;
        float ssum = 0.f, qsum = 0.f;
#pragma unroll
        for (int g = 0; g < RG; ++g) {
            ssum += ls[(g * C4 + cc) * 16 + k];
            qsum += ls[(g * C4 + cc) * 16 + 8 + k];
        }
        atomicAdd(&stats[t], ssum);
        atomicAdd(&stats[C + t], qsum);
    }
}

// ---------------- classifier: per-block coef from stats + fused GraphNorm+ELU ----------------
__global__ __launch_bounds__(256) void k_cls(const ushort* __restrict__ X,
                                             const float* __restrict__ stats,
                                             const float* __restrict__ gw,
                                             const float* __restrict__ gb,
                                             const float* __restrict__ gms,
                                             const float* __restrict__ Wc,
                                             const float* __restrict__ bc,
                                             float* __restrict__ out, int Nn) {
    __shared__ __align__(16) float ls[16 * 132];
    __shared__ __align__(16) float wT[13 * 132];
    __shared__ __align__(16) float ABs[256];
    __shared__ float bS[13];
    int t = threadIdx.x;
    int n0 = blockIdx.x * 16;
    if (t < 128) {
        float inv = 1.f / (float)Nn;
        float mean = stats[t] * inv;
        float cm = mean * gms[t];
        float var = stats[128 + t] * inv - 2.f * cm * mean + cm * cm;
        float A = gw[t] * rsqrtf(var + GEPS);
        ABs[t] = A;
        ABs[128 + t] = gb[t] - A * cm;
    }
    for (int i = t; i < 128 * 13; i += 256) {
        int k = i / 13, j = i - k * 13;
        wT[j * 132 + k] = Wc[i];
    }
    if (t < 13) bS[t] = bc[t];
    __syncthreads();
    const unsigned int* xu = (const unsigned int*)X;
    for (int idx = t; idx < 16 * 64; idx += 256) {
        int r = idx >> 6, ku = idx & 63;
        int row = n0 + r;
        float vx = 0.f, vy = 0.f;
        if (row < Nn) {
            float2 v = unpack_bf2(xu[(size_t)row * 64 + ku]);
            int k = 2 * ku;
            vx = elu_fast(fmaf(ABs[k], v.x, ABs[128 + k]));
            vy = elu_fast(fmaf(ABs[k + 1], v.y, ABs[128 + k + 1]));
        }
        ls[r * 132 + 2 * ku] = vx;
        ls[r * 132 + 2 * ku + 1] = vy;
    }
    __syncthreads();
    if (t < 208) {
        int r = t / 13, j = t - r * 13;
        int row = n0 + r;
        if (row < Nn) {
            float acc = bS[j];
            const float* lr = &ls[r * 132];
            const float* wr = &wT[j * 132];
#pragma unroll 8
            for (int k = 0; k < 128; k += 4) {
                float4 a = *(const float4*)&lr[k];
                float4 b = *(const float4*)&wr[k];
                acc = fmaf(a.x, b.x, fmaf(a.y, b.y, fmaf(a.z, b.z, fmaf(a.w, b.w, acc))));
            }
            out[(size_t)row * 13 + j] = acc;
        }
    }
}

extern "C" void kernel_launch(void* const* d_in, const int* in_sizes, int n_in, void* d_out,
                              int out_size, void* d_ws, size_t ws_size, hipStream_t stream) {
    const float* x = (const float*)d_in[0];
    const int* edge_index = (const int*)d_in[1];
    const float* edge_attr = (const float*)d_in[2];
    const float* W1 = (const float*)d_in[3];
    const float* We1 = (const float*)d_in[4];
    const float* as1 = (const float*)d_in[5];
    const float* ad1 = (const float*)d_in[6];
    const float* ae1 = (const float*)d_in[7];
    const float* b1 = (const float*)d_in[8];
    const float* gn1_w = (const float*)d_in[9];
    const float* gn1_b = (const float*)d_in[10];
    const float* gn1_ms = (const float*)d_in[11];
    const float* W2 = (const float*)d_in[12];
    const float* We2 = (const float*)d_in[13];
    const float* as2 = (const float*)d_in[14];
    const float* ad2 = (const float*)d_in[15];
    const float* ae2 = (const float*)d_in[16];
    const float* b2 = (const float*)d_in[17];
    const float* gn2_w = (const float*)d_in[18];
    const float* gn2_b = (const float*)d_in[19];
    const float* gn2_ms = (const float*)d_in[20];
    const float* Wc = (const float*)d_in[21];
    const float* bc = (const float*)d_in[22];

    const int N = in_sizes[0] / 3;
    const int E = in_sizes[1] / 2;
    const int* srcv = edge_index;
    const int* dstv = edge_index + E;

    // ---- workspace carve (256B-aligned, byte-based) ----
    char* w = (char*)d_ws;
    auto carveB = [&](size_t bytes) -> void* {
        void* p = (void*)w;
        w += ((bytes + 255) / 256) * 256;
        return p;
    };
    // zeroed region first:
    int* deg = (int*)carveB((size_t)N * 4);
    float* ea_sum = (float*)carveB(8);
    float* mom = (float*)carveB(36 * 4);
    float* statsB = (float*)carveB(256 * 4);
    char* zero_end = w;
    // not zeroed:
    int* row_ptr = (int*)carveB((size_t)(N + 1) * 4);
    int* bsum = (int*)carveB(1024 * 4);
    float4* ed4 = (float4*)carveB((size_t)E * 16);
    float* C1 = (float*)carveB(8 * 4);
    float* C2 = (float*)carveB(4 * 4);
    float* Ps = (float*)carveB(12 * 4);
    float* Pd = (float*)carveB(12 * 4);
    float* lE1 = (float*)carveB(4 * 4);
    float* lE2 = (float*)carveB(2 * 4);
    uint4* Bfrag = (uint4*)carveB(4096 * 16);
    float4* ndr = (float4*)carveB((size_t)N * 32);        // {x0,x1,x2,_}|{as1(4)} per node
    float* al_d1 = (float*)carveB((size_t)N * 4 * 4);
    float* al_s2 = (float*)carveB((size_t)N * 2 * 4);
    float* al_d2 = (float*)carveB((size_t)N * 2 * 4);
    float4* uarr = (float4*)carveB((size_t)N * 4 * 16);   // per-node per-head u
    ushort* h2b = (ushort*)carveB((size_t)N * 128 * 2);   // bf16 h2
    ushort* out2b = (ushort*)carveB((size_t)N * 128 * 2); // bf16 layer-2 output

    hipMemsetAsync(deg, 0, (size_t)(zero_end - (char*)deg), stream);

    const int nb1 = (N + 1023) / 1024;
    const int ebl = (E + 255) / 256;

    k_pre<<<17 + 256, 256, 0, stream>>>(W1, as1, ad1, edge_attr, dstv, W2, We1, ae1, We2, ae2,
                                        ea_sum, deg, Bfrag, C1, C2, Ps, Pd, E);
    k_scan1<<<nb1, 1024, 0, stream>>>(deg, row_ptr, bsum, N);
    k_scan23<<<nb1, 1024, 0, stream>>>(row_ptr, bsum, ea_sum, C1, C2, Ps, Pd, x, ndr, al_d1,
                                       lE1, lE2, N, E);
    k_scat<<<ebl, 256, 0, stream>>>(dstv, srcv, edge_attr, row_ptr, deg, ed4, E);
    k_agg1<<<(N + 15) / 16, 256, 0, stream>>>(ndr, row_ptr, ed4, al_d1, C1, lE1, (float*)uarr,
                                              N);
    k_mom<<<128, 256, 0, stream>>>(uarr, mom, N * 4);
    k_gemm2_mfma<<<(N + 63) / 64, 256, 0, stream>>>(uarr, mom, W1, b1, gn1_w, gn1_b, gn1_ms,
                                                    Bfrag, as2, ad2, h2b, al_s2, al_d2, N);
    k_agg2<<<(N + 3) / 4, 256, 0, stream>>>(h2b, row_ptr, ed4, al_s2, al_d2, C2, lE2, b2,
                                            out2b, N);
    k_stats_bf<16><<<256, 256, 0, stream>>>(out2b, statsB, N);
    k_cls<<<(N + 15) / 16, 256, 0, stream>>>(out2b, statsB, gn2_w, gn2_b, gn2_ms, Wc, bc,
                                             (float*)d_out, N);
}